// Round 1
// baseline (464.017 us; speedup 1.0000x reference)
//
#include <hip/hip_runtime.h>
#include <hip/hip_bf16.h>

typedef __attribute__((ext_vector_type(8))) short bf16x8;
typedef __attribute__((ext_vector_type(4))) float f32x4;
typedef __attribute__((ext_vector_type(4))) unsigned u32x4;

#define CDIM 1024
#define DDIM 1024
#define TDIM 1024
#define BK 32

// out[b,d,t] = sum_c x[b,c,t] * w[subj[b],c,d]
// Per block: 128(d) x 128(t) output tile for one batch. 4 waves, each 64x64.
// bf16x3 split precision: v = hi + lo (each bf16), compute hi*hi + hi*lo + lo*hi.
// LDS tiles: row = d (or t), 64 shorts/row = granules g0-3 (hi, k=0..31) and
// g4-7 (lo). Granule index XOR-swizzled with (row&7) -> conflict-free b128.
__global__ __launch_bounds__(256, 2)
void subject_gemm(const float* __restrict__ x, const int* __restrict__ subj,
                  const float* __restrict__ w, float* __restrict__ out)
{
    __shared__ short Wt[128 * 64];
    __shared__ short Xt[128 * 64];

    const int bid = blockIdx.x;
    const int b = bid >> 6;          // batch-major for L2 reuse
    const int r = bid & 63;
    const int dtile = (r >> 3) << 7;
    const int ttile = (r & 7) << 7;

    const int s = subj[b];
    const float* __restrict__ wB = w + (size_t)s * (CDIM * DDIM);
    const float* __restrict__ xB = x + (size_t)b * (CDIM * TDIM);

    const int tid = threadIdx.x;
    const int lane = tid & 63;
    const int wave = tid >> 6;

    // ---- staging assignment: thread owns one column (d or t), 16 c's ----
    const int sd = tid & 127;            // column within tile
    const int sc = (tid >> 7) << 4;      // c start within slab: 0 or 16
    const float* wp = wB + dtile + sd;
    const float* xp = xB + ttile + sd;
    short* wlds = Wt + sd * 64;
    short* xlds = Xt + sd * 64;
    const int swz = sd & 7;

    // ---- fragment assignment ----
    const int wr = (wave >> 1) << 6;     // wave d offset: 0/64
    const int wc = (wave & 1) << 6;      // wave t offset: 0/64
    const int fr = lane & 15;
    const int fg = lane >> 4;            // k-granule 0..3
    const int r7 = fr & 7;               // row&7 is fr&7 for all frag rows
    const int offH = (fg ^ r7) << 3;         // shorts
    const int offL = ((fg + 4) ^ r7) << 3;   // shorts

    f32x4 acc[4][4] = {};

    for (int k0 = 0; k0 < CDIM; k0 += BK) {
        // global loads (coalesced 256B/wave per instr; issued before barrier
        // so they overlap previous iteration's MFMA)
        float vw[16], vx[16];
        #pragma unroll
        for (int j = 0; j < 16; ++j) {
            const int c = k0 + sc + j;
            vw[j] = wp[c << 10];
            vx[j] = xp[c << 10];
        }
        // hi/lo split by truncation: hi = top16(f), lo = top16(f - hi)
        u32x4 hwv[2], lwv[2], hxv[2], lxv[2];
        #pragma unroll
        for (int p = 0; p < 8; ++p) {
            {
                const float f0 = vw[2 * p], f1 = vw[2 * p + 1];
                const unsigned u0 = __float_as_uint(f0), u1 = __float_as_uint(f1);
                hwv[p >> 2][p & 3] = (u0 >> 16) | (u1 & 0xFFFF0000u);
                const float l0 = f0 - __uint_as_float(u0 & 0xFFFF0000u);
                const float l1 = f1 - __uint_as_float(u1 & 0xFFFF0000u);
                lwv[p >> 2][p & 3] = (__float_as_uint(l0) >> 16) | (__float_as_uint(l1) & 0xFFFF0000u);
            }
            {
                const float f0 = vx[2 * p], f1 = vx[2 * p + 1];
                const unsigned u0 = __float_as_uint(f0), u1 = __float_as_uint(f1);
                hxv[p >> 2][p & 3] = (u0 >> 16) | (u1 & 0xFFFF0000u);
                const float l0 = f0 - __uint_as_float(u0 & 0xFFFF0000u);
                const float l1 = f1 - __uint_as_float(u1 & 0xFFFF0000u);
                lxv[p >> 2][p & 3] = (__float_as_uint(l0) >> 16) | (__float_as_uint(l1) & 0xFFFF0000u);
            }
        }

        __syncthreads();   // previous iteration's LDS reads complete
        #pragma unroll
        for (int g2 = 0; g2 < 2; ++g2) {
            const int g = (sc >> 3) + g2;
            *(u32x4*)(wlds + (((g    ) ^ swz) << 3)) = hwv[g2];
            *(u32x4*)(wlds + (((g + 4) ^ swz) << 3)) = lwv[g2];
            *(u32x4*)(xlds + (((g    ) ^ swz) << 3)) = hxv[g2];
            *(u32x4*)(xlds + (((g + 4) ^ swz) << 3)) = lxv[g2];
        }
        __syncthreads();   // tile staged

        bf16x8 ah[4], al[4], bh[4], bl[4];
        #pragma unroll
        for (int m = 0; m < 4; ++m) {
            const short* wrow = Wt + (wr + m * 16 + fr) * 64;
            ah[m] = *(const bf16x8*)(wrow + offH);
            al[m] = *(const bf16x8*)(wrow + offL);
            const short* xrow = Xt + (wc + m * 16 + fr) * 64;
            bh[m] = *(const bf16x8*)(xrow + offH);
            bl[m] = *(const bf16x8*)(xrow + offL);
        }
        #pragma unroll
        for (int m = 0; m < 4; ++m) {
            #pragma unroll
            for (int n = 0; n < 4; ++n) {
                acc[m][n] = __builtin_amdgcn_mfma_f32_16x16x32_bf16(ah[m], bh[n], acc[m][n], 0, 0, 0);
                acc[m][n] = __builtin_amdgcn_mfma_f32_16x16x32_bf16(ah[m], bl[n], acc[m][n], 0, 0, 0);
                acc[m][n] = __builtin_amdgcn_mfma_f32_16x16x32_bf16(al[m], bh[n], acc[m][n], 0, 0, 0);
            }
        }
    }

    // epilogue: C/D layout col = lane&15 (t), row = (lane>>4)*4 + q (d)
    float* __restrict__ oB = out + (size_t)b * (DDIM * TDIM)
                           + (size_t)(dtile + wr) * TDIM + (ttile + wc);
    #pragma unroll
    for (int m = 0; m < 4; ++m) {
        #pragma unroll
        for (int n = 0; n < 4; ++n) {
            #pragma unroll
            for (int q = 0; q < 4; ++q) {
                const int d = m * 16 + (fg << 2) + q;
                const int t = n * 16 + fr;
                oB[d * TDIM + t] = acc[m][n][q];
            }
        }
    }
}

extern "C" void kernel_launch(void* const* d_in, const int* in_sizes, int n_in,
                              void* d_out, int out_size, void* d_ws, size_t ws_size,
                              hipStream_t stream) {
    const float* x = (const float*)d_in[0];
    const int* subjects = (const int*)d_in[1];
    const float* w = (const float*)d_in[2];
    float* out = (float*)d_out;
    subject_gemm<<<dim3(64 * 8 * 8), dim3(256), 0, stream>>>(x, subjects, w, out);
}